// Round 1
// baseline (4376.463 us; speedup 1.0000x reference)
//
#include <hip/hip_runtime.h>
#include <math.h>

#define NN 50000
#define NF 512
#define NH 128
#define NC 10
#define NE 800000

// ---------------- edge dtype detection + conversion ----------------
// If edge_index is int64 little-endian, every odd 32-bit word is 0 (values < 50000).
__global__ void detect_dtype_kernel(const int* __restrict__ ei, int* __restrict__ flag) {
    __shared__ int any_nonzero;
    if (threadIdx.x == 0) any_nonzero = 0;
    __syncthreads();
    // scan odd words 1,3,...,2047 (1024 samples)
    for (int i = threadIdx.x; i < 1024; i += 256) {
        if (ei[2 * i + 1] != 0) any_nonzero = 1;
    }
    __syncthreads();
    if (threadIdx.x == 0) *flag = (any_nonzero == 0) ? 1 : 0;  // 1 => int64
}

__global__ void convert_edges_kernel(const int* __restrict__ ei, int* __restrict__ src,
                                     int* __restrict__ dst, const int* __restrict__ flag) {
    int e = blockIdx.x * 256 + threadIdx.x;
    if (e >= NE) return;
    int s, d;
    if (*flag) {  // int64 layout: ei32[2*k] is low word of element k
        s = ei[2 * e];
        d = ei[2 * (NE + e)];
    } else {
        s = ei[e];
        d = ei[NE + e];
    }
    s = min(max(s, 0), NN - 1);
    d = min(max(d, 0), NN - 1);
    src[e] = s;
    dst[e] = d;
}

// ---------------- degree / dinv ----------------
__global__ void deg_kernel(const int* __restrict__ dst, float* __restrict__ deg) {
    int e = blockIdx.x * 256 + threadIdx.x;
    if (e < NE) atomicAdd(&deg[dst[e]], 1.0f);
}

__global__ void dinv_kernel(float* __restrict__ deg_dinv) {
    int i = blockIdx.x * 256 + threadIdx.x;
    if (i < NN) {
        float d = deg_dinv[i] + 1.0f;  // +1 self-loop; always >= 1
        deg_dinv[i] = rsqrtf(d);
    }
}

// ---------------- GEMM: C[nrows x 128] = A[nrows x K] @ W[K x 128] ----------------
__global__ __launch_bounds__(256) void gemm_kernel(const float* __restrict__ A,
                                                   const float* __restrict__ W,
                                                   float* __restrict__ C, int nrows, int K) {
    __shared__ __align__(16) float As[64 * 68];   // 64 rows x 64 k, pad stride 68
    __shared__ __align__(16) float Ws[64 * 128];  // 64 k x 128 cols
    const int tid = threadIdx.x;
    const int tx = tid & 31;   // col quad: cols tx*4 .. tx*4+3
    const int ty = tid >> 5;   // 0..7: owns rows ty*8 .. ty*8+7
    const int brow = blockIdx.x * 64;

    float4 acc[8];
#pragma unroll
    for (int i = 0; i < 8; ++i) acc[i] = make_float4(0.f, 0.f, 0.f, 0.f);

    for (int k0 = 0; k0 < K; k0 += 64) {
        // stage A tile: 1024 float4
#pragma unroll
        for (int i = 0; i < 4; ++i) {
            int idx = tid + i * 256;   // float4 index
            int r = idx >> 4;          // row in tile
            int kq = idx & 15;         // k-quad
            int gr = brow + r;
            float4 v = make_float4(0.f, 0.f, 0.f, 0.f);
            if (gr < nrows) v = *(const float4*)(A + (size_t)gr * K + k0 + kq * 4);
            *(float4*)(As + r * 68 + kq * 4) = v;
        }
        // stage W tile: 2048 float4
#pragma unroll
        for (int i = 0; i < 8; ++i) {
            int idx = tid + i * 256;
            int r = idx >> 5;          // k within tile
            int cq = idx & 31;
            *(float4*)(Ws + r * 128 + cq * 4) = *(const float4*)(W + (size_t)(k0 + r) * 128 + cq * 4);
        }
        __syncthreads();
#pragma unroll 16
        for (int kk = 0; kk < 64; ++kk) {
            float4 wv = reinterpret_cast<const float4*>(Ws)[kk * 32 + tx];
#pragma unroll
            for (int i = 0; i < 8; ++i) {
                float a = As[(ty * 8 + i) * 68 + kk];
                acc[i].x += a * wv.x;
                acc[i].y += a * wv.y;
                acc[i].z += a * wv.z;
                acc[i].w += a * wv.w;
            }
        }
        __syncthreads();
    }
#pragma unroll
    for (int i = 0; i < 8; ++i) {
        int gr = brow + ty * 8 + i;
        if (gr < nrows) *(float4*)(C + (size_t)gr * 128 + tx * 4) = acc[i];
    }
}

// ---------------- edge scatter: agg[dst] += norm * h[src] ----------------
__global__ __launch_bounds__(256) void scatter_kernel(const float* __restrict__ h,
                                                      const int* __restrict__ src,
                                                      const int* __restrict__ dst,
                                                      const float* __restrict__ dinv,
                                                      float* __restrict__ agg) {
    long long gid = (long long)blockIdx.x * 256 + threadIdx.x;
    int e = (int)(gid >> 5);
    int c = ((int)gid & 31) * 4;
    if (e >= NE) return;
    int s = src[e];
    int d = dst[e];
    float norm = dinv[s] * dinv[d];
    float4 hv = *(const float4*)(h + (size_t)s * NH + c);
    float* o = agg + (size_t)d * NH + c;
    atomicAdd(o + 0, hv.x * norm);
    atomicAdd(o + 1, hv.y * norm);
    atomicAdd(o + 2, hv.z * norm);
    atomicAdd(o + 3, hv.w * norm);
}

// ---------------- fuse: agg = maybe_relu(agg + dinv^2*h + b) ----------------
__global__ __launch_bounds__(256) void fuse_kernel(float* __restrict__ agg,
                                                   const float* __restrict__ h,
                                                   const float* __restrict__ dinv,
                                                   const float* __restrict__ b, int relu) {
    long long gid = (long long)blockIdx.x * 256 + threadIdx.x;
    int i = (int)(gid >> 5);
    int c = ((int)gid & 31) * 4;
    if (i >= NN) return;
    float di = dinv[i];
    float sl = di * di;
    float4 a = *(const float4*)(agg + (size_t)i * NH + c);
    float4 hv = *(const float4*)(h + (size_t)i * NH + c);
    float4 bb = *(const float4*)(b + c);
    float4 v;
    v.x = a.x + sl * hv.x + bb.x;
    v.y = a.y + sl * hv.y + bb.y;
    v.z = a.z + sl * hv.z + bb.z;
    v.w = a.w + sl * hv.w + bb.w;
    if (relu) {
        v.x = fmaxf(v.x, 0.f);
        v.y = fmaxf(v.y, 0.f);
        v.z = fmaxf(v.z, 0.f);
        v.w = fmaxf(v.w, 0.f);
    }
    *(float4*)(agg + (size_t)i * NH + c) = v;
}

// ---------------- final: logits = x3 @ Wl + bl; log_softmax ----------------
__global__ __launch_bounds__(256) void final_kernel(const float* __restrict__ x3,
                                                    const float* __restrict__ Wl,
                                                    const float* __restrict__ bl,
                                                    float* __restrict__ out) {
    __shared__ float Wls[NH * NC];
    __shared__ float bls[NC];
    for (int i = threadIdx.x; i < NH * NC; i += 256) Wls[i] = Wl[i];
    if (threadIdx.x < NC) bls[threadIdx.x] = bl[threadIdx.x];
    __syncthreads();
    int n = blockIdx.x * 256 + threadIdx.x;
    if (n >= NN) return;
    float logit[NC];
#pragma unroll
    for (int c = 0; c < NC; ++c) logit[c] = bls[c];
    const float4* xr = (const float4*)(x3 + (size_t)n * NH);
#pragma unroll 8
    for (int kq = 0; kq < 32; ++kq) {
        float4 xv = xr[kq];
#pragma unroll
        for (int c = 0; c < NC; ++c) {
            logit[c] += xv.x * Wls[(kq * 4 + 0) * NC + c] + xv.y * Wls[(kq * 4 + 1) * NC + c] +
                        xv.z * Wls[(kq * 4 + 2) * NC + c] + xv.w * Wls[(kq * 4 + 3) * NC + c];
        }
    }
    float m = logit[0];
#pragma unroll
    for (int c = 1; c < NC; ++c) m = fmaxf(m, logit[c]);
    float s = 0.f;
#pragma unroll
    for (int c = 0; c < NC; ++c) s += expf(logit[c] - m);
    float lse = m + logf(s);
#pragma unroll
    for (int c = 0; c < NC; ++c) out[(size_t)n * NC + c] = logit[c] - lse;
}

extern "C" void kernel_launch(void* const* d_in, const int* in_sizes, int n_in,
                              void* d_out, int out_size, void* d_ws, size_t ws_size,
                              hipStream_t stream) {
    const float* x = (const float*)d_in[0];
    const int* ei = (const int*)d_in[1];
    const float* W1 = (const float*)d_in[2];
    const float* b1 = (const float*)d_in[3];
    const float* W2 = (const float*)d_in[4];
    const float* b2 = (const float*)d_in[5];
    const float* W3 = (const float*)d_in[6];
    const float* b3 = (const float*)d_in[7];
    const float* Wl = (const float*)d_in[8];
    const float* bl = (const float*)d_in[9];
    float* out = (float*)d_out;

    char* ws = (char*)d_ws;
    size_t off = 0;
    auto alloc = [&](size_t bytes) {
        void* p = ws + off;
        off = (off + bytes + 255) & ~(size_t)255;
        return p;
    };
    float* dinv = (float*)alloc((size_t)NN * 4);       // deg, then dinv (in place)
    int* flag = (int*)alloc(256);
    int* src = (int*)alloc((size_t)NE * 4);
    int* dst = (int*)alloc((size_t)NE * 4);
    float* h = (float*)alloc((size_t)NN * NH * 4);
    float* agg = (float*)alloc((size_t)NN * NH * 4);
    (void)ws_size;

    // edge index normalization
    detect_dtype_kernel<<<1, 256, 0, stream>>>(ei, flag);
    convert_edges_kernel<<<(NE + 255) / 256, 256, 0, stream>>>(ei, src, dst, flag);

    // degree + dinv
    hipMemsetAsync(dinv, 0, (size_t)NN * 4, stream);
    deg_kernel<<<(NE + 255) / 256, 256, 0, stream>>>(dst, dinv);
    dinv_kernel<<<(NN + 255) / 256, 256, 0, stream>>>(dinv);

    const int gemm_grid = (NN + 63) / 64;
    const int scat_grid = (int)(((long long)NE * 32 + 255) / 256);
    const int fuse_grid = (int)(((long long)NN * 32 + 255) / 256);

    // layer 1: h = x @ W1 ; agg = scatter ; x1 = relu(agg + dinv^2 h + b1) (in agg)
    gemm_kernel<<<gemm_grid, 256, 0, stream>>>(x, W1, h, NN, NF);
    hipMemsetAsync(agg, 0, (size_t)NN * NH * 4, stream);
    scatter_kernel<<<scat_grid, 256, 0, stream>>>(h, src, dst, dinv, agg);
    fuse_kernel<<<fuse_grid, 256, 0, stream>>>(agg, h, dinv, b1, 1);

    // layer 2
    gemm_kernel<<<gemm_grid, 256, 0, stream>>>(agg, W2, h, NN, NH);
    hipMemsetAsync(agg, 0, (size_t)NN * NH * 4, stream);
    scatter_kernel<<<scat_grid, 256, 0, stream>>>(h, src, dst, dinv, agg);
    fuse_kernel<<<fuse_grid, 256, 0, stream>>>(agg, h, dinv, b2, 1);

    // layer 3 (no relu)
    gemm_kernel<<<gemm_grid, 256, 0, stream>>>(agg, W3, h, NN, NH);
    hipMemsetAsync(agg, 0, (size_t)NN * NH * 4, stream);
    scatter_kernel<<<scat_grid, 256, 0, stream>>>(h, src, dst, dinv, agg);
    fuse_kernel<<<fuse_grid, 256, 0, stream>>>(agg, h, dinv, b3, 0);

    // classifier + log_softmax
    final_kernel<<<(NN + 255) / 256, 256, 0, stream>>>(agg, Wl, bl, out);
}

// Round 2
// 500.675 us; speedup vs baseline: 8.7411x; 8.7411x over previous
//
#include <hip/hip_runtime.h>
#include <math.h>

#define NN 50000
#define NF 512
#define NH 128
#define NC 10
#define NE 800000

// ---------------- edge dtype detection + conversion ----------------
__global__ void detect_dtype_kernel(const int* __restrict__ ei, int* __restrict__ flag) {
    __shared__ int any_nonzero;
    if (threadIdx.x == 0) any_nonzero = 0;
    __syncthreads();
    for (int i = threadIdx.x; i < 1024; i += 256) {
        if (ei[2 * i + 1] != 0) any_nonzero = 1;
    }
    __syncthreads();
    if (threadIdx.x == 0) *flag = (any_nonzero == 0) ? 1 : 0;  // 1 => int64
}

__global__ void convert_edges_kernel(const int* __restrict__ ei, int* __restrict__ src,
                                     int* __restrict__ dst, const int* __restrict__ flag) {
    int e = blockIdx.x * 256 + threadIdx.x;
    if (e >= NE) return;
    int s, d;
    if (*flag) {
        s = ei[2 * e];
        d = ei[2 * (NE + e)];
    } else {
        s = ei[e];
        d = ei[NE + e];
    }
    s = min(max(s, 0), NN - 1);
    d = min(max(d, 0), NN - 1);
    src[e] = s;
    dst[e] = d;
}

// ---------------- degree count (int) ----------------
__global__ void deg_kernel(const int* __restrict__ dst, int* __restrict__ deg) {
    int e = blockIdx.x * 256 + threadIdx.x;
    if (e < NE) atomicAdd(&deg[dst[e]], 1);
}

__global__ void dinv_kernel(const int* __restrict__ deg, float* __restrict__ dinv) {
    int i = blockIdx.x * 256 + threadIdx.x;
    if (i < NN) dinv[i] = rsqrtf((float)deg[i] + 1.0f);  // +1 self-loop
}

// ---------------- exclusive prefix sum of deg -> row_ptr ----------------
#define SCAN_ELEMS 2048
#define SCAN_BLOCKS ((NN + SCAN_ELEMS - 1) / SCAN_ELEMS)  // 25

__global__ __launch_bounds__(256) void scan1_kernel(const int* __restrict__ deg,
                                                    int* __restrict__ row_ptr,
                                                    int* __restrict__ block_sums) {
    __shared__ int ldata[256];
    const int t = threadIdx.x;
    const int base = blockIdx.x * SCAN_ELEMS;
    int v[8];
    int sum = 0;
#pragma unroll
    for (int j = 0; j < 8; ++j) {
        int idx = base + t * 8 + j;
        v[j] = (idx < NN) ? deg[idx] : 0;
        sum += v[j];
    }
    ldata[t] = sum;
    __syncthreads();
    for (int off = 1; off < 256; off <<= 1) {
        int x = (t >= off) ? ldata[t - off] : 0;
        __syncthreads();
        if (t >= off) ldata[t] += x;
        __syncthreads();
    }
    int excl = ldata[t] - sum;
    if (t == 255) block_sums[blockIdx.x] = ldata[255];
    int run = excl;
#pragma unroll
    for (int j = 0; j < 8; ++j) {
        int idx = base + t * 8 + j;
        if (idx < NN) row_ptr[idx] = run;
        run += v[j];
    }
}

__global__ void scan2_kernel(int* __restrict__ block_sums) {
    if (blockIdx.x == 0 && threadIdx.x == 0) {
        int run = 0;
        for (int i = 0; i < SCAN_BLOCKS; ++i) {
            int t = block_sums[i];
            block_sums[i] = run;
            run += t;
        }
    }
}

__global__ __launch_bounds__(256) void scan3_kernel(int* __restrict__ row_ptr,
                                                    const int* __restrict__ block_sums) {
    const int add = block_sums[blockIdx.x];
    const int base = blockIdx.x * SCAN_ELEMS;
#pragma unroll
    for (int j = 0; j < 8; ++j) {
        int idx = base + threadIdx.x * 8 + j;
        if (idx < NN) row_ptr[idx] += add;
    }
    if (blockIdx.x == 0 && threadIdx.x == 0) row_ptr[NN] = NE;
}

// ---------------- fill CSR (sorted by dst) with precomputed edge weight ----------------
__global__ void fill_csr_kernel(const int* __restrict__ src, const int* __restrict__ dst,
                                const float* __restrict__ dinv, const int* __restrict__ row_ptr,
                                int* __restrict__ fill, int* __restrict__ csr_src,
                                float* __restrict__ csr_w) {
    int e = blockIdx.x * 256 + threadIdx.x;
    if (e >= NE) return;
    int s = src[e];
    int d = dst[e];
    int pos = atomicAdd(&fill[d], 1);
    int idx = row_ptr[d] + pos;
    csr_src[idx] = s;
    csr_w[idx] = dinv[s] * dinv[d];
}

// ---------------- GEMM: C[nrows x 128] = A[nrows x K] @ W[K x 128] ----------------
__global__ __launch_bounds__(256) void gemm_kernel(const float* __restrict__ A,
                                                   const float* __restrict__ W,
                                                   float* __restrict__ C, int nrows, int K) {
    __shared__ __align__(16) float As[64 * 68];
    __shared__ __align__(16) float Ws[64 * 128];
    const int tid = threadIdx.x;
    const int tx = tid & 31;
    const int ty = tid >> 5;
    const int brow = blockIdx.x * 64;

    float4 acc[8];
#pragma unroll
    for (int i = 0; i < 8; ++i) acc[i] = make_float4(0.f, 0.f, 0.f, 0.f);

    for (int k0 = 0; k0 < K; k0 += 64) {
#pragma unroll
        for (int i = 0; i < 4; ++i) {
            int idx = tid + i * 256;
            int r = idx >> 4;
            int kq = idx & 15;
            int gr = brow + r;
            float4 v = make_float4(0.f, 0.f, 0.f, 0.f);
            if (gr < nrows) v = *(const float4*)(A + (size_t)gr * K + k0 + kq * 4);
            *(float4*)(As + r * 68 + kq * 4) = v;
        }
#pragma unroll
        for (int i = 0; i < 8; ++i) {
            int idx = tid + i * 256;
            int r = idx >> 5;
            int cq = idx & 31;
            *(float4*)(Ws + r * 128 + cq * 4) = *(const float4*)(W + (size_t)(k0 + r) * 128 + cq * 4);
        }
        __syncthreads();
#pragma unroll 16
        for (int kk = 0; kk < 64; ++kk) {
            float4 wv = reinterpret_cast<const float4*>(Ws)[kk * 32 + tx];
#pragma unroll
            for (int i = 0; i < 8; ++i) {
                float a = As[(ty * 8 + i) * 68 + kk];
                acc[i].x += a * wv.x;
                acc[i].y += a * wv.y;
                acc[i].z += a * wv.z;
                acc[i].w += a * wv.w;
            }
        }
        __syncthreads();
    }
#pragma unroll
    for (int i = 0; i < 8; ++i) {
        int gr = brow + ty * 8 + i;
        if (gr < nrows) *(float4*)(C + (size_t)gr * 128 + tx * 4) = acc[i];
    }
}

// ---------------- aggregate (CSR gather) + self-loop + bias + relu ----------------
__global__ __launch_bounds__(256) void aggregate_kernel(
    const float* __restrict__ h, const int* __restrict__ row_ptr,
    const int* __restrict__ csr_src, const float* __restrict__ csr_w,
    const float* __restrict__ dinv, const float* __restrict__ b,
    float* __restrict__ out, int relu) {
    const int node = (blockIdx.x * 256 + threadIdx.x) >> 6;  // one wave per node
    const int lane = threadIdx.x & 63;
    if (node >= NN) return;
    const int beg = row_ptr[node];
    const int end = row_ptr[node + 1];
    const float2* __restrict__ hp = (const float2*)h;

    float ax = 0.f, ay = 0.f;
    int e = beg;
    for (; e + 1 < end; e += 2) {
        int s0 = csr_src[e];
        int s1 = csr_src[e + 1];
        float w0 = csr_w[e];
        float w1 = csr_w[e + 1];
        float2 v0 = hp[(size_t)s0 * 64 + lane];
        float2 v1 = hp[(size_t)s1 * 64 + lane];
        ax += w0 * v0.x + w1 * v1.x;
        ay += w0 * v0.y + w1 * v1.y;
    }
    if (e < end) {
        int s0 = csr_src[e];
        float w0 = csr_w[e];
        float2 v0 = hp[(size_t)s0 * 64 + lane];
        ax += w0 * v0.x;
        ay += w0 * v0.y;
    }
    float di = dinv[node];
    float sl = di * di;
    float2 hv = hp[(size_t)node * 64 + lane];
    float2 bb = ((const float2*)b)[lane];
    float vx = ax + sl * hv.x + bb.x;
    float vy = ay + sl * hv.y + bb.y;
    if (relu) {
        vx = fmaxf(vx, 0.f);
        vy = fmaxf(vy, 0.f);
    }
    float2 o;
    o.x = vx;
    o.y = vy;
    ((float2*)out)[(size_t)node * 64 + lane] = o;
}

// ---------------- final: logits = x3 @ Wl + bl; log_softmax ----------------
__global__ __launch_bounds__(256) void final_kernel(const float* __restrict__ x3,
                                                    const float* __restrict__ Wl,
                                                    const float* __restrict__ bl,
                                                    float* __restrict__ out) {
    __shared__ float Wls[NH * NC];
    __shared__ float bls[NC];
    for (int i = threadIdx.x; i < NH * NC; i += 256) Wls[i] = Wl[i];
    if (threadIdx.x < NC) bls[threadIdx.x] = bl[threadIdx.x];
    __syncthreads();
    int n = blockIdx.x * 256 + threadIdx.x;
    if (n >= NN) return;
    float logit[NC];
#pragma unroll
    for (int c = 0; c < NC; ++c) logit[c] = bls[c];
    const float4* xr = (const float4*)(x3 + (size_t)n * NH);
#pragma unroll 8
    for (int kq = 0; kq < 32; ++kq) {
        float4 xv = xr[kq];
#pragma unroll
        for (int c = 0; c < NC; ++c) {
            logit[c] += xv.x * Wls[(kq * 4 + 0) * NC + c] + xv.y * Wls[(kq * 4 + 1) * NC + c] +
                        xv.z * Wls[(kq * 4 + 2) * NC + c] + xv.w * Wls[(kq * 4 + 3) * NC + c];
        }
    }
    float m = logit[0];
#pragma unroll
    for (int c = 1; c < NC; ++c) m = fmaxf(m, logit[c]);
    float s = 0.f;
#pragma unroll
    for (int c = 0; c < NC; ++c) s += expf(logit[c] - m);
    float lse = m + logf(s);
#pragma unroll
    for (int c = 0; c < NC; ++c) out[(size_t)n * NC + c] = logit[c] - lse;
}

extern "C" void kernel_launch(void* const* d_in, const int* in_sizes, int n_in,
                              void* d_out, int out_size, void* d_ws, size_t ws_size,
                              hipStream_t stream) {
    const float* x = (const float*)d_in[0];
    const int* ei = (const int*)d_in[1];
    const float* W1 = (const float*)d_in[2];
    const float* b1 = (const float*)d_in[3];
    const float* W2 = (const float*)d_in[4];
    const float* b2 = (const float*)d_in[5];
    const float* W3 = (const float*)d_in[6];
    const float* b3 = (const float*)d_in[7];
    const float* Wl = (const float*)d_in[8];
    const float* bl = (const float*)d_in[9];
    float* out = (float*)d_out;

    char* ws = (char*)d_ws;
    size_t off = 0;
    auto alloc = [&](size_t bytes) {
        void* p = ws + off;
        off = (off + bytes + 255) & ~(size_t)255;
        return p;
    };
    int* flag = (int*)alloc(256);
    int* src = (int*)alloc((size_t)NE * 4);
    int* dst = (int*)alloc((size_t)NE * 4);
    int* deg = (int*)alloc((size_t)NN * 4);
    float* dinv = (float*)alloc((size_t)NN * 4);
    int* row_ptr = (int*)alloc((size_t)(NN + 1) * 4);
    int* fill = (int*)alloc((size_t)NN * 4);
    int* block_sums = (int*)alloc((size_t)SCAN_BLOCKS * 4 + 256);
    int* csr_src = (int*)alloc((size_t)NE * 4);
    float* csr_w = (float*)alloc((size_t)NE * 4);
    float* h = (float*)alloc((size_t)NN * NH * 4);
    float* agg = (float*)alloc((size_t)NN * NH * 4);
    (void)ws_size;

    // --- edge normalization + CSR build (once, reused for 3 layers) ---
    detect_dtype_kernel<<<1, 256, 0, stream>>>(ei, flag);
    convert_edges_kernel<<<(NE + 255) / 256, 256, 0, stream>>>(ei, src, dst, flag);
    hipMemsetAsync(deg, 0, (size_t)NN * 4, stream);
    hipMemsetAsync(fill, 0, (size_t)NN * 4, stream);
    deg_kernel<<<(NE + 255) / 256, 256, 0, stream>>>(dst, deg);
    dinv_kernel<<<(NN + 255) / 256, 256, 0, stream>>>(deg, dinv);
    scan1_kernel<<<SCAN_BLOCKS, 256, 0, stream>>>(deg, row_ptr, block_sums);
    scan2_kernel<<<1, 64, 0, stream>>>(block_sums);
    scan3_kernel<<<SCAN_BLOCKS, 256, 0, stream>>>(row_ptr, block_sums);
    fill_csr_kernel<<<(NE + 255) / 256, 256, 0, stream>>>(src, dst, dinv, row_ptr, fill,
                                                          csr_src, csr_w);

    const int gemm_grid = (NN + 63) / 64;
    const int agg_grid = (NN * 64 + 255) / 256;  // one wave per node, 4 waves/block

    // layer 1
    gemm_kernel<<<gemm_grid, 256, 0, stream>>>(x, W1, h, NN, NF);
    aggregate_kernel<<<agg_grid, 256, 0, stream>>>(h, row_ptr, csr_src, csr_w, dinv, b1, agg, 1);
    // layer 2
    gemm_kernel<<<gemm_grid, 256, 0, stream>>>(agg, W2, h, NN, NH);
    aggregate_kernel<<<agg_grid, 256, 0, stream>>>(h, row_ptr, csr_src, csr_w, dinv, b2, agg, 1);
    // layer 3 (no relu)
    gemm_kernel<<<gemm_grid, 256, 0, stream>>>(agg, W3, h, NN, NH);
    aggregate_kernel<<<agg_grid, 256, 0, stream>>>(h, row_ptr, csr_src, csr_w, dinv, b3, agg, 0);

    // classifier + log_softmax
    final_kernel<<<(NN + 255) / 256, 256, 0, stream>>>(agg, Wl, bl, out);
}

// Round 3
// 349.747 us; speedup vs baseline: 12.5132x; 1.4315x over previous
//
#include <hip/hip_runtime.h>
#include <math.h>

#define NN 50000
#define NF 512
#define NH 128
#define NC 10
#define NE 800000

typedef __attribute__((ext_vector_type(8))) short short8_t;
typedef __attribute__((ext_vector_type(4))) float f32x4;

__device__ inline ushort f2bf(float f) {
    union { float f; uint u; } v;
    v.f = f;
    uint r = v.u + 0x7FFF + ((v.u >> 16) & 1);
    return (ushort)(r >> 16);
}
__device__ inline uint pk2(float a, float b) {
    return (uint)f2bf(a) | ((uint)f2bf(b) << 16);
}
__device__ inline float bflo(uint u) {
    union { uint u; float f; } v;
    v.u = u << 16;
    return v.f;
}
__device__ inline float bfhi(uint u) {
    union { uint u; float f; } v;
    v.u = u & 0xFFFF0000u;
    return v.f;
}

// ---------------- edge dtype detection + conversion ----------------
__global__ void detect_dtype_kernel(const int* __restrict__ ei, int* __restrict__ flag) {
    __shared__ int any_nonzero;
    if (threadIdx.x == 0) any_nonzero = 0;
    __syncthreads();
    for (int i = threadIdx.x; i < 1024; i += 256) {
        if (ei[2 * i + 1] != 0) any_nonzero = 1;
    }
    __syncthreads();
    if (threadIdx.x == 0) *flag = (any_nonzero == 0) ? 1 : 0;  // 1 => int64
}

__global__ void convert_edges_kernel(const int* __restrict__ ei, int* __restrict__ src,
                                     int* __restrict__ dst, const int* __restrict__ flag) {
    int e = blockIdx.x * 256 + threadIdx.x;
    if (e >= NE) return;
    int s, d;
    if (*flag) {
        s = ei[2 * e];
        d = ei[2 * (NE + e)];
    } else {
        s = ei[e];
        d = ei[NE + e];
    }
    s = min(max(s, 0), NN - 1);
    d = min(max(d, 0), NN - 1);
    src[e] = s;
    dst[e] = d;
}

// ---------------- degree count (int) ----------------
__global__ void deg_kernel(const int* __restrict__ dst, int* __restrict__ deg) {
    int e = blockIdx.x * 256 + threadIdx.x;
    if (e < NE) atomicAdd(&deg[dst[e]], 1);
}

__global__ void dinv_kernel(const int* __restrict__ deg, float* __restrict__ dinv) {
    int i = blockIdx.x * 256 + threadIdx.x;
    if (i < NN) dinv[i] = rsqrtf((float)deg[i] + 1.0f);  // +1 self-loop
}

// ---------------- exclusive prefix sum of deg -> row_ptr ----------------
#define SCAN_ELEMS 2048
#define SCAN_BLOCKS ((NN + SCAN_ELEMS - 1) / SCAN_ELEMS)  // 25

__global__ __launch_bounds__(256) void scan1_kernel(const int* __restrict__ deg,
                                                    int* __restrict__ row_ptr,
                                                    int* __restrict__ block_sums) {
    __shared__ int ldata[256];
    const int t = threadIdx.x;
    const int base = blockIdx.x * SCAN_ELEMS;
    int v[8];
    int sum = 0;
#pragma unroll
    for (int j = 0; j < 8; ++j) {
        int idx = base + t * 8 + j;
        v[j] = (idx < NN) ? deg[idx] : 0;
        sum += v[j];
    }
    ldata[t] = sum;
    __syncthreads();
    for (int off = 1; off < 256; off <<= 1) {
        int x = (t >= off) ? ldata[t - off] : 0;
        __syncthreads();
        if (t >= off) ldata[t] += x;
        __syncthreads();
    }
    int excl = ldata[t] - sum;
    if (t == 255) block_sums[blockIdx.x] = ldata[255];
    int run = excl;
#pragma unroll
    for (int j = 0; j < 8; ++j) {
        int idx = base + t * 8 + j;
        if (idx < NN) row_ptr[idx] = run;
        run += v[j];
    }
}

__global__ void scan2_kernel(int* __restrict__ block_sums) {
    if (blockIdx.x == 0 && threadIdx.x == 0) {
        int run = 0;
        for (int i = 0; i < SCAN_BLOCKS; ++i) {
            int t = block_sums[i];
            block_sums[i] = run;
            run += t;
        }
    }
}

__global__ __launch_bounds__(256) void scan3_kernel(int* __restrict__ row_ptr,
                                                    const int* __restrict__ block_sums) {
    const int add = block_sums[blockIdx.x];
    const int base = blockIdx.x * SCAN_ELEMS;
#pragma unroll
    for (int j = 0; j < 8; ++j) {
        int idx = base + threadIdx.x * 8 + j;
        if (idx < NN) row_ptr[idx] += add;
    }
    if (blockIdx.x == 0 && threadIdx.x == 0) row_ptr[NN] = NE;
}

// ---------------- fill CSR (sorted by dst) with precomputed edge weight ----------------
__global__ void fill_csr_kernel(const int* __restrict__ src, const int* __restrict__ dst,
                                const float* __restrict__ dinv, const int* __restrict__ row_ptr,
                                int* __restrict__ fill, int* __restrict__ csr_src,
                                float* __restrict__ csr_w) {
    int e = blockIdx.x * 256 + threadIdx.x;
    if (e >= NE) return;
    int s = src[e];
    int d = dst[e];
    int pos = atomicAdd(&fill[d], 1);
    int idx = row_ptr[d] + pos;
    csr_src[idx] = s;
    csr_w[idx] = dinv[s] * dinv[d];
}

// ---------------- weight transpose + bf16 convert: W[K][128] -> Wt[128][K] ----------------
__global__ __launch_bounds__(128) void wtrans_kernel(const float* __restrict__ W,
                                                     ushort* __restrict__ Wt, int K) {
    __shared__ float tile[8][132];
    const int k0 = blockIdx.x * 8;
#pragma unroll
    for (int i = 0; i < 8; ++i) {
        int idx = threadIdx.x + i * 128;
        int r = idx >> 7;
        int c = idx & 127;
        tile[r][c] = W[(size_t)(k0 + r) * NH + c];
    }
    __syncthreads();
    const int c = threadIdx.x;
    uint4 o;
    o.x = pk2(tile[0][c], tile[1][c]);
    o.y = pk2(tile[2][c], tile[3][c]);
    o.z = pk2(tile[4][c], tile[5][c]);
    o.w = pk2(tile[6][c], tile[7][c]);
    *(uint4*)&Wt[(size_t)c * K + k0] = o;
}

// ---------------- MFMA GEMM: H[nrows x 128](bf16) = A[nrows x K](f32) @ W ----------------
#define BM 64
#define BK 64
#define LDST 72   // LDS stride in bf16 units (144B = 9*16B)
#define ESTRIDE 144

__global__ __launch_bounds__(256) void gemm_mfma_kernel(const float* __restrict__ A,
                                                        const ushort* __restrict__ Wt,
                                                        ushort* __restrict__ Hout, int nrows,
                                                        int K) {
    __shared__ __align__(16) ushort smem[(BM + NH) * LDST];  // As | Bs, reused as epilogue
    ushort* As = smem;
    ushort* Bs = smem + BM * LDST;
    const int tid = threadIdx.x;
    const int wave = tid >> 6;
    const int lane = tid & 63;
    const int l15 = lane & 15;
    const int l4 = lane >> 4;
    const int brow = blockIdx.x * BM;

    f32x4 zero4 = {0.f, 0.f, 0.f, 0.f};
    f32x4 acc[4][2];
#pragma unroll
    for (int rb = 0; rb < 4; ++rb)
#pragma unroll
        for (int cb = 0; cb < 2; ++cb) acc[rb][cb] = zero4;

    for (int k0 = 0; k0 < K; k0 += BK) {
        // stage A tile (f32 -> bf16): 64 rows x 64 k
#pragma unroll
        for (int i = 0; i < 4; ++i) {
            int idx = tid + i * 256;
            int r = idx >> 4;   // row in tile
            int q = idx & 15;   // float4 slot within row
            int gr = brow + r;
            float4 f;
            if (gr < nrows)
                f = *(const float4*)(A + (size_t)gr * K + k0 + q * 4);
            else
                f = make_float4(0.f, 0.f, 0.f, 0.f);
            uint2 w;
            w.x = pk2(f.x, f.y);
            w.y = pk2(f.z, f.w);
            *(uint2*)&As[r * LDST + q * 4] = w;
        }
        // stage Wt tile: 128 cols x 64 k (bf16 copy)
#pragma unroll
        for (int i = 0; i < 4; ++i) {
            int idx = tid + i * 256;
            int r = idx >> 3;  // col (row of Wt)
            int s = idx & 7;   // uint4 slot
            *(uint4*)&Bs[r * LDST + s * 8] = *(const uint4*)&Wt[(size_t)r * K + k0 + s * 8];
        }
        __syncthreads();
#pragma unroll
        for (int ks = 0; ks < 2; ++ks) {
            short8_t af[4], bf[2];
#pragma unroll
            for (int rb = 0; rb < 4; ++rb)
                af[rb] = *(const short8_t*)&As[(rb * 16 + l15) * LDST + ks * 32 + l4 * 8];
#pragma unroll
            for (int cb = 0; cb < 2; ++cb)
                bf[cb] = *(const short8_t*)&Bs[(wave * 32 + cb * 16 + l15) * LDST + ks * 32 + l4 * 8];
#pragma unroll
            for (int rb = 0; rb < 4; ++rb)
#pragma unroll
                for (int cb = 0; cb < 2; ++cb)
                    acc[rb][cb] = __builtin_amdgcn_mfma_f32_16x16x32_bf16(af[rb], bf[cb],
                                                                          acc[rb][cb], 0, 0, 0);
        }
        __syncthreads();
    }

    // epilogue: assemble bf16 tile in LDS (stride 144 = bank-spread, 16B-aligned rows)
    ushort* Es = smem;
#pragma unroll
    for (int rb = 0; rb < 4; ++rb)
#pragma unroll
        for (int cb = 0; cb < 2; ++cb)
#pragma unroll
            for (int j = 0; j < 4; ++j) {
                int r = rb * 16 + l4 * 4 + j;
                int c = wave * 32 + cb * 16 + l15;
                Es[r * ESTRIDE + c] = f2bf(acc[rb][cb][j]);
            }
    __syncthreads();
#pragma unroll
    for (int i = 0; i < 4; ++i) {
        int idx = tid + i * 256;
        int r = idx >> 4;   // row
        int s = idx & 15;   // uint4 slot (8 bf16)
        if (brow + r < nrows)
            *(uint4*)&Hout[(size_t)(brow + r) * NH + s * 8] = *(const uint4*)&Es[r * ESTRIDE + s * 8];
    }
}

// ---------------- aggregate (CSR gather, bf16 h) + self-loop + bias + relu ----------------
__global__ __launch_bounds__(256) void aggregate_kernel(
    const ushort* __restrict__ h, const int* __restrict__ row_ptr,
    const int* __restrict__ csr_src, const float* __restrict__ csr_w,
    const float* __restrict__ dinv, const float* __restrict__ b,
    float* __restrict__ out, int relu) {
    const int node = (blockIdx.x * 256 + threadIdx.x) >> 6;  // one wave per node
    const int lane = threadIdx.x & 63;
    if (node >= NN) return;
    const uint* __restrict__ hp = (const uint*)h;  // 2 bf16 per uint, 64 per row
    const int beg = row_ptr[node];
    const int end = row_ptr[node + 1];

    float ax = 0.f, ay = 0.f;
    int e = beg;
    for (; e + 1 < end; e += 2) {
        int s0 = csr_src[e];
        int s1 = csr_src[e + 1];
        float w0 = csr_w[e];
        float w1 = csr_w[e + 1];
        uint v0 = hp[(size_t)s0 * 64 + lane];
        uint v1 = hp[(size_t)s1 * 64 + lane];
        ax += w0 * bflo(v0) + w1 * bflo(v1);
        ay += w0 * bfhi(v0) + w1 * bfhi(v1);
    }
    if (e < end) {
        int s0 = csr_src[e];
        float w0 = csr_w[e];
        uint v0 = hp[(size_t)s0 * 64 + lane];
        ax += w0 * bflo(v0);
        ay += w0 * bfhi(v0);
    }
    float di = dinv[node];
    float sl = di * di;
    uint hv = hp[(size_t)node * 64 + lane];
    float2 bb = ((const float2*)b)[lane];
    float vx = ax + sl * bflo(hv) + bb.x;
    float vy = ay + sl * bfhi(hv) + bb.y;
    if (relu) {
        vx = fmaxf(vx, 0.f);
        vy = fmaxf(vy, 0.f);
    }
    float2 o;
    o.x = vx;
    o.y = vy;
    ((float2*)out)[(size_t)node * 64 + lane] = o;
}

// ---------------- final: logits = x3 @ Wl + bl; log_softmax ----------------
__global__ __launch_bounds__(256) void final_kernel(const float* __restrict__ x3,
                                                    const float* __restrict__ Wl,
                                                    const float* __restrict__ bl,
                                                    float* __restrict__ out) {
    __shared__ float Wls[NH * NC];
    __shared__ float bls[NC];
    for (int i = threadIdx.x; i < NH * NC; i += 256) Wls[i] = Wl[i];
    if (threadIdx.x < NC) bls[threadIdx.x] = bl[threadIdx.x];
    __syncthreads();
    int n = blockIdx.x * 256 + threadIdx.x;
    if (n >= NN) return;
    float logit[NC];
#pragma unroll
    for (int c = 0; c < NC; ++c) logit[c] = bls[c];
    const float4* xr = (const float4*)(x3 + (size_t)n * NH);
#pragma unroll 8
    for (int kq = 0; kq < 32; ++kq) {
        float4 xv = xr[kq];
#pragma unroll
        for (int c = 0; c < NC; ++c) {
            logit[c] += xv.x * Wls[(kq * 4 + 0) * NC + c] + xv.y * Wls[(kq * 4 + 1) * NC + c] +
                        xv.z * Wls[(kq * 4 + 2) * NC + c] + xv.w * Wls[(kq * 4 + 3) * NC + c];
        }
    }
    float m = logit[0];
#pragma unroll
    for (int c = 1; c < NC; ++c) m = fmaxf(m, logit[c]);
    float s = 0.f;
#pragma unroll
    for (int c = 0; c < NC; ++c) s += expf(logit[c] - m);
    float lse = m + logf(s);
#pragma unroll
    for (int c = 0; c < NC; ++c) out[(size_t)n * NC + c] = logit[c] - lse;
}

extern "C" void kernel_launch(void* const* d_in, const int* in_sizes, int n_in,
                              void* d_out, int out_size, void* d_ws, size_t ws_size,
                              hipStream_t stream) {
    const float* x = (const float*)d_in[0];
    const int* ei = (const int*)d_in[1];
    const float* W1 = (const float*)d_in[2];
    const float* b1 = (const float*)d_in[3];
    const float* W2 = (const float*)d_in[4];
    const float* b2 = (const float*)d_in[5];
    const float* W3 = (const float*)d_in[6];
    const float* b3 = (const float*)d_in[7];
    const float* Wl = (const float*)d_in[8];
    const float* bl = (const float*)d_in[9];
    float* out = (float*)d_out;

    char* ws = (char*)d_ws;
    size_t off = 0;
    auto alloc = [&](size_t bytes) {
        void* p = ws + off;
        off = (off + bytes + 255) & ~(size_t)255;
        return p;
    };
    int* flag = (int*)alloc(256);
    int* src = (int*)alloc((size_t)NE * 4);
    int* dst = (int*)alloc((size_t)NE * 4);
    int* deg = (int*)alloc((size_t)NN * 4);
    float* dinv = (float*)alloc((size_t)NN * 4);
    int* row_ptr = (int*)alloc((size_t)(NN + 1) * 4);
    int* fill = (int*)alloc((size_t)NN * 4);
    int* block_sums = (int*)alloc((size_t)SCAN_BLOCKS * 4 + 256);
    int* csr_src = (int*)alloc((size_t)NE * 4);
    float* csr_w = (float*)alloc((size_t)NE * 4);
    ushort* h = (ushort*)alloc((size_t)NN * NH * 2);     // bf16 pre-aggregation features
    float* act = (float*)alloc((size_t)NN * NH * 4);     // f32 activations
    ushort* Wt1 = (ushort*)alloc((size_t)NF * NH * 2);
    ushort* Wt2 = (ushort*)alloc((size_t)NH * NH * 2);
    ushort* Wt3 = (ushort*)alloc((size_t)NH * NH * 2);
    (void)ws_size;

    // --- edge normalization + CSR build (once, reused for 3 layers) ---
    detect_dtype_kernel<<<1, 256, 0, stream>>>(ei, flag);
    convert_edges_kernel<<<(NE + 255) / 256, 256, 0, stream>>>(ei, src, dst, flag);
    hipMemsetAsync(deg, 0, (size_t)NN * 4, stream);
    hipMemsetAsync(fill, 0, (size_t)NN * 4, stream);
    deg_kernel<<<(NE + 255) / 256, 256, 0, stream>>>(dst, deg);
    dinv_kernel<<<(NN + 255) / 256, 256, 0, stream>>>(deg, dinv);
    scan1_kernel<<<SCAN_BLOCKS, 256, 0, stream>>>(deg, row_ptr, block_sums);
    scan2_kernel<<<1, 64, 0, stream>>>(block_sums);
    scan3_kernel<<<SCAN_BLOCKS, 256, 0, stream>>>(row_ptr, block_sums);
    fill_csr_kernel<<<(NE + 255) / 256, 256, 0, stream>>>(src, dst, dinv, row_ptr, fill,
                                                          csr_src, csr_w);

    // --- weight transpose+convert ---
    wtrans_kernel<<<NF / 8, 128, 0, stream>>>(W1, Wt1, NF);
    wtrans_kernel<<<NH / 8, 128, 0, stream>>>(W2, Wt2, NH);
    wtrans_kernel<<<NH / 8, 128, 0, stream>>>(W3, Wt3, NH);

    const int gemm_grid = (NN + BM - 1) / BM;
    const int agg_grid = (NN * 64 + 255) / 256;

    // layer 1
    gemm_mfma_kernel<<<gemm_grid, 256, 0, stream>>>(x, Wt1, h, NN, NF);
    aggregate_kernel<<<agg_grid, 256, 0, stream>>>(h, row_ptr, csr_src, csr_w, dinv, b1, act, 1);
    // layer 2
    gemm_mfma_kernel<<<gemm_grid, 256, 0, stream>>>(act, Wt2, h, NN, NH);
    aggregate_kernel<<<agg_grid, 256, 0, stream>>>(h, row_ptr, csr_src, csr_w, dinv, b2, act, 1);
    // layer 3 (no relu)
    gemm_mfma_kernel<<<gemm_grid, 256, 0, stream>>>(act, Wt3, h, NN, NH);
    aggregate_kernel<<<agg_grid, 256, 0, stream>>>(h, row_ptr, csr_src, csr_w, dinv, b3, act, 0);

    // classifier + log_softmax
    final_kernel<<<(NN + 255) / 256, 256, 0, stream>>>(act, Wl, bl, out);
}

// Round 4
// 289.878 us; speedup vs baseline: 15.0976x; 1.2065x over previous
//
#include <hip/hip_runtime.h>
#include <math.h>

#define NN 50000
#define NF 512
#define NH 128
#define NC 10
#define NE 800000

typedef __attribute__((ext_vector_type(8))) short short8_t;
typedef __attribute__((ext_vector_type(4))) float f32x4;

__device__ inline ushort f2bf(float f) {
    union { float f; uint u; } v;
    v.f = f;
    uint r = v.u + 0x7FFF + ((v.u >> 16) & 1);
    return (ushort)(r >> 16);
}
__device__ inline uint pk2(float a, float b) {
    return (uint)f2bf(a) | ((uint)f2bf(b) << 16);
}
__device__ inline float bflo(uint u) {
    union { uint u; float f; } v;
    v.u = u << 16;
    return v.f;
}
__device__ inline float bfhi(uint u) {
    union { uint u; float f; } v;
    v.u = u & 0xFFFF0000u;
    return v.f;
}

// ---------------- edge dtype detection + conversion ----------------
__global__ void detect_dtype_kernel(const int* __restrict__ ei, int* __restrict__ flag) {
    __shared__ int any_nonzero;
    if (threadIdx.x == 0) any_nonzero = 0;
    __syncthreads();
    for (int i = threadIdx.x; i < 1024; i += 256) {
        if (ei[2 * i + 1] != 0) any_nonzero = 1;
    }
    __syncthreads();
    if (threadIdx.x == 0) *flag = (any_nonzero == 0) ? 1 : 0;  // 1 => int64
}

__global__ void convert_edges_kernel(const int* __restrict__ ei, int* __restrict__ src,
                                     int* __restrict__ dst, const int* __restrict__ flag) {
    int e = blockIdx.x * 256 + threadIdx.x;
    if (e >= NE) return;
    int s, d;
    if (*flag) {
        s = ei[2 * e];
        d = ei[2 * (NE + e)];
    } else {
        s = ei[e];
        d = ei[NE + e];
    }
    s = min(max(s, 0), NN - 1);
    d = min(max(d, 0), NN - 1);
    src[e] = s;
    dst[e] = d;
}

// ---------------- degree count (int) ----------------
__global__ void deg_kernel(const int* __restrict__ dst, int* __restrict__ deg) {
    int e = blockIdx.x * 256 + threadIdx.x;
    if (e < NE) atomicAdd(&deg[dst[e]], 1);
}

__global__ void dinv_kernel(const int* __restrict__ deg, float* __restrict__ dinv) {
    int i = blockIdx.x * 256 + threadIdx.x;
    if (i < NN) dinv[i] = rsqrtf((float)deg[i] + 1.0f);  // +1 self-loop
}

// ---------------- exclusive prefix sum of deg -> row_ptr ----------------
#define SCAN_ELEMS 2048
#define SCAN_BLOCKS ((NN + SCAN_ELEMS - 1) / SCAN_ELEMS)  // 25

__global__ __launch_bounds__(256) void scan1_kernel(const int* __restrict__ deg,
                                                    int* __restrict__ row_ptr,
                                                    int* __restrict__ block_sums) {
    __shared__ int ldata[256];
    const int t = threadIdx.x;
    const int base = blockIdx.x * SCAN_ELEMS;
    int v[8];
    int sum = 0;
#pragma unroll
    for (int j = 0; j < 8; ++j) {
        int idx = base + t * 8 + j;
        v[j] = (idx < NN) ? deg[idx] : 0;
        sum += v[j];
    }
    ldata[t] = sum;
    __syncthreads();
    for (int off = 1; off < 256; off <<= 1) {
        int x = (t >= off) ? ldata[t - off] : 0;
        __syncthreads();
        if (t >= off) ldata[t] += x;
        __syncthreads();
    }
    int excl = ldata[t] - sum;
    if (t == 255) block_sums[blockIdx.x] = ldata[255];
    int run = excl;
#pragma unroll
    for (int j = 0; j < 8; ++j) {
        int idx = base + t * 8 + j;
        if (idx < NN) row_ptr[idx] = run;
        run += v[j];
    }
}

__global__ void scan2_kernel(int* __restrict__ block_sums) {
    if (blockIdx.x == 0 && threadIdx.x == 0) {
        int run = 0;
        for (int i = 0; i < SCAN_BLOCKS; ++i) {
            int t = block_sums[i];
            block_sums[i] = run;
            run += t;
        }
    }
}

__global__ __launch_bounds__(256) void scan3_kernel(int* __restrict__ row_ptr,
                                                    const int* __restrict__ block_sums) {
    const int add = block_sums[blockIdx.x];
    const int base = blockIdx.x * SCAN_ELEMS;
#pragma unroll
    for (int j = 0; j < 8; ++j) {
        int idx = base + threadIdx.x * 8 + j;
        if (idx < NN) row_ptr[idx] += add;
    }
    if (blockIdx.x == 0 && threadIdx.x == 0) row_ptr[NN] = NE;
}

// ---------------- fill CSR (sorted by dst) with precomputed edge weight ----------------
__global__ void fill_csr_kernel(const int* __restrict__ src, const int* __restrict__ dst,
                                const float* __restrict__ dinv, const int* __restrict__ row_ptr,
                                int* __restrict__ fill, int* __restrict__ csr_src,
                                float* __restrict__ csr_w) {
    int e = blockIdx.x * 256 + threadIdx.x;
    if (e >= NE) return;
    int s = src[e];
    int d = dst[e];
    int pos = atomicAdd(&fill[d], 1);
    int idx = row_ptr[d] + pos;
    csr_src[idx] = s;
    csr_w[idx] = dinv[s] * dinv[d];
}

// ---------------- weight transpose + bf16 convert: W[K][128] -> Wt[128][K] ----------------
__global__ __launch_bounds__(128) void wtrans_kernel(const float* __restrict__ W,
                                                     ushort* __restrict__ Wt, int K) {
    __shared__ float tile[8][132];
    const int k0 = blockIdx.x * 8;
#pragma unroll
    for (int i = 0; i < 8; ++i) {
        int idx = threadIdx.x + i * 128;
        int r = idx >> 7;
        int c = idx & 127;
        tile[r][c] = W[(size_t)(k0 + r) * NH + c];
    }
    __syncthreads();
    const int c = threadIdx.x;
    uint4 o;
    o.x = pk2(tile[0][c], tile[1][c]);
    o.y = pk2(tile[2][c], tile[3][c]);
    o.z = pk2(tile[4][c], tile[5][c]);
    o.w = pk2(tile[6][c], tile[7][c]);
    *(uint4*)&Wt[(size_t)c * K + k0] = o;
}

// ---------------- MFMA GEMM: H[nrows x 128](bf16) = A[nrows x K] @ W ----------------
// BM=32, BK=64, XOR-swizzled LDS (16B chunk index ^ (row&7))
#define BM 32

template <int A_F32>
__global__ __launch_bounds__(256) void gemm_mfma_kernel(const void* __restrict__ Ap,
                                                        const ushort* __restrict__ Wt,
                                                        ushort* __restrict__ Hout, int nrows,
                                                        int K) {
    __shared__ __align__(16) ushort smem[BM * 64 + NH * 64];  // As | Bs; reused as epilogue
    ushort* As = smem;            // [32][64] bf16, swizzled
    ushort* Bs = smem + BM * 64;  // [128][64] bf16, swizzled
    const int tid = threadIdx.x;
    const int wave = tid >> 6;
    const int lane = tid & 63;
    const int l15 = lane & 15;
    const int l4 = lane >> 4;
    const int brow = blockIdx.x * BM;

    f32x4 zero4 = {0.f, 0.f, 0.f, 0.f};
    f32x4 acc[2][2];
#pragma unroll
    for (int rb = 0; rb < 2; ++rb)
#pragma unroll
        for (int cb = 0; cb < 2; ++cb) acc[rb][cb] = zero4;

    for (int k0 = 0; k0 < K; k0 += 64) {
        // stage A tile: 32 rows x 8 chunks(16B), one chunk per thread
        {
            int r = tid >> 3;
            int s = tid & 7;
            int gr = brow + r;
            uint4 w = make_uint4(0, 0, 0, 0);
            if (A_F32) {
                if (gr < nrows) {
                    const float* A = (const float*)Ap;
                    float4 f0 = *(const float4*)(A + (size_t)gr * K + k0 + s * 8);
                    float4 f1 = *(const float4*)(A + (size_t)gr * K + k0 + s * 8 + 4);
                    w.x = pk2(f0.x, f0.y);
                    w.y = pk2(f0.z, f0.w);
                    w.z = pk2(f1.x, f1.y);
                    w.w = pk2(f1.z, f1.w);
                }
            } else {
                if (gr < nrows) {
                    const ushort* A = (const ushort*)Ap;
                    w = *(const uint4*)(A + (size_t)gr * K + k0 + s * 8);
                }
            }
            *(uint4*)&As[r * 64 + ((s ^ (r & 7)) * 8)] = w;
        }
        // stage B tile: 128 rows x 8 chunks, 4 chunks per thread
#pragma unroll
        for (int i = 0; i < 4; ++i) {
            int idx = tid + i * 256;
            int r = idx >> 3;
            int s = idx & 7;
            uint4 w = *(const uint4*)&Wt[(size_t)r * K + k0 + s * 8];
            *(uint4*)&Bs[r * 64 + ((s ^ (r & 7)) * 8)] = w;
        }
        __syncthreads();
#pragma unroll
        for (int ks = 0; ks < 2; ++ks) {
            short8_t af[2], bf[2];
#pragma unroll
            for (int rb = 0; rb < 2; ++rb) {
                int r = rb * 16 + l15;
                af[rb] = *(const short8_t*)&As[r * 64 + (((ks * 4 + l4) ^ (r & 7)) * 8)];
            }
#pragma unroll
            for (int cb = 0; cb < 2; ++cb) {
                int r = wave * 32 + cb * 16 + l15;
                bf[cb] = *(const short8_t*)&Bs[r * 64 + (((ks * 4 + l4) ^ (r & 7)) * 8)];
            }
#pragma unroll
            for (int rb = 0; rb < 2; ++rb)
#pragma unroll
                for (int cb = 0; cb < 2; ++cb)
                    acc[rb][cb] = __builtin_amdgcn_mfma_f32_16x16x32_bf16(af[rb], bf[cb],
                                                                          acc[rb][cb], 0, 0, 0);
        }
        __syncthreads();
    }

    // epilogue: assemble bf16 tile in LDS [32][136], then coalesced store
    ushort* Es = smem;
#pragma unroll
    for (int rb = 0; rb < 2; ++rb)
#pragma unroll
        for (int cb = 0; cb < 2; ++cb)
#pragma unroll
            for (int j = 0; j < 4; ++j) {
                int r = rb * 16 + l4 * 4 + j;
                int c = wave * 32 + cb * 16 + l15;
                Es[r * 136 + c] = f2bf(acc[rb][cb][j]);
            }
    __syncthreads();
#pragma unroll
    for (int i = 0; i < 2; ++i) {
        int idx = tid + i * 256;
        int r = idx >> 4;
        int s = idx & 15;
        if (brow + r < nrows)
            *(uint4*)&Hout[(size_t)(brow + r) * NH + s * 8] = *(const uint4*)&Es[r * 136 + s * 8];
    }
}

// ---------------- aggregate: 4-way edge-ILP CSR gather + self-loop + bias (+relu) ----------
__device__ inline void fma8(float* acc, float w, uint4 v) {
    acc[0] += w * bflo(v.x);
    acc[1] += w * bfhi(v.x);
    acc[2] += w * bflo(v.y);
    acc[3] += w * bfhi(v.y);
    acc[4] += w * bflo(v.z);
    acc[5] += w * bfhi(v.z);
    acc[6] += w * bflo(v.w);
    acc[7] += w * bfhi(v.w);
}

template <int OUT_F32, int RELU>
__global__ __launch_bounds__(256) void aggregate_kernel(
    const ushort* __restrict__ h, const int* __restrict__ row_ptr,
    const int* __restrict__ csr_src, const float* __restrict__ csr_w,
    const float* __restrict__ dinv, const float* __restrict__ b, void* __restrict__ outp) {
    const int node = (blockIdx.x * 256 + threadIdx.x) >> 6;  // one wave per node
    if (node >= NN) return;
    const int lane = threadIdx.x & 63;
    const int g = lane >> 4;    // edge group 0..3
    const int li = lane & 15;   // feature chunk (8 bf16)
    const uint4* __restrict__ hp = (const uint4*)h;  // 16 uint4 per 128-feat row
    const int beg = row_ptr[node];
    const int end = row_ptr[node + 1];

    float acc[8];
#pragma unroll
    for (int k = 0; k < 8; ++k) acc[k] = 0.f;

    for (int e0 = beg; e0 < end; e0 += 8) {
        int e1 = e0 + g;
        if (e1 < end) {
            int s = csr_src[e1];
            float w = csr_w[e1];
            fma8(acc, w, hp[(size_t)s * 16 + li]);
        }
        int e2 = e0 + 4 + g;
        if (e2 < end) {
            int s = csr_src[e2];
            float w = csr_w[e2];
            fma8(acc, w, hp[(size_t)s * 16 + li]);
        }
    }
    // reduce across the 4 groups (lanes li, 16+li, 32+li, 48+li hold same feature slice)
#pragma unroll
    for (int k = 0; k < 8; ++k) {
        acc[k] += __shfl_xor(acc[k], 16);
        acc[k] += __shfl_xor(acc[k], 32);
    }
    if (g == 0) {
        uint4 hv = hp[(size_t)node * 16 + li];
        float di = dinv[node];
        float sl = di * di;
        float4 b0 = *(const float4*)(b + li * 8);
        float4 b1 = *(const float4*)(b + li * 8 + 4);
        float v0 = acc[0] + sl * bflo(hv.x) + b0.x;
        float v1 = acc[1] + sl * bfhi(hv.x) + b0.y;
        float v2 = acc[2] + sl * bflo(hv.y) + b0.z;
        float v3 = acc[3] + sl * bfhi(hv.y) + b0.w;
        float v4 = acc[4] + sl * bflo(hv.z) + b1.x;
        float v5 = acc[5] + sl * bfhi(hv.z) + b1.y;
        float v6 = acc[6] + sl * bflo(hv.w) + b1.z;
        float v7 = acc[7] + sl * bfhi(hv.w) + b1.w;
        if (RELU) {
            v0 = fmaxf(v0, 0.f); v1 = fmaxf(v1, 0.f); v2 = fmaxf(v2, 0.f); v3 = fmaxf(v3, 0.f);
            v4 = fmaxf(v4, 0.f); v5 = fmaxf(v5, 0.f); v6 = fmaxf(v6, 0.f); v7 = fmaxf(v7, 0.f);
        }
        if (OUT_F32) {
            float* out = (float*)outp;
            float4 o0 = {v0, v1, v2, v3};
            float4 o1 = {v4, v5, v6, v7};
            *(float4*)(out + (size_t)node * NH + li * 8) = o0;
            *(float4*)(out + (size_t)node * NH + li * 8 + 4) = o1;
        } else {
            ushort* out = (ushort*)outp;
            uint4 o;
            o.x = pk2(v0, v1);
            o.y = pk2(v2, v3);
            o.z = pk2(v4, v5);
            o.w = pk2(v6, v7);
            *(uint4*)(out + (size_t)node * NH + li * 8) = o;
        }
    }
}

// ---------------- final: logits = x3 @ Wl + bl; log_softmax ----------------
__global__ __launch_bounds__(256) void final_kernel(const float* __restrict__ x3,
                                                    const float* __restrict__ Wl,
                                                    const float* __restrict__ bl,
                                                    float* __restrict__ out) {
    __shared__ float Wls[NH * NC];
    __shared__ float bls[NC];
    for (int i = threadIdx.x; i < NH * NC; i += 256) Wls[i] = Wl[i];
    if (threadIdx.x < NC) bls[threadIdx.x] = bl[threadIdx.x];
    __syncthreads();
    int n = blockIdx.x * 256 + threadIdx.x;
    if (n >= NN) return;
    float logit[NC];
#pragma unroll
    for (int c = 0; c < NC; ++c) logit[c] = bls[c];
    const float4* xr = (const float4*)(x3 + (size_t)n * NH);
#pragma unroll 8
    for (int kq = 0; kq < 32; ++kq) {
        float4 xv = xr[kq];
#pragma unroll
        for (int c = 0; c < NC; ++c) {
            logit[c] += xv.x * Wls[(kq * 4 + 0) * NC + c] + xv.y * Wls[(kq * 4 + 1) * NC + c] +
                        xv.z * Wls[(kq * 4 + 2) * NC + c] + xv.w * Wls[(kq * 4 + 3) * NC + c];
        }
    }
    float m = logit[0];
#pragma unroll
    for (int c = 1; c < NC; ++c) m = fmaxf(m, logit[c]);
    float s = 0.f;
#pragma unroll
    for (int c = 0; c < NC; ++c) s += expf(logit[c] - m);
    float lse = m + logf(s);
#pragma unroll
    for (int c = 0; c < NC; ++c) out[(size_t)n * NC + c] = logit[c] - lse;
}

extern "C" void kernel_launch(void* const* d_in, const int* in_sizes, int n_in,
                              void* d_out, int out_size, void* d_ws, size_t ws_size,
                              hipStream_t stream) {
    const float* x = (const float*)d_in[0];
    const int* ei = (const int*)d_in[1];
    const float* W1 = (const float*)d_in[2];
    const float* b1 = (const float*)d_in[3];
    const float* W2 = (const float*)d_in[4];
    const float* b2 = (const float*)d_in[5];
    const float* W3 = (const float*)d_in[6];
    const float* b3 = (const float*)d_in[7];
    const float* Wl = (const float*)d_in[8];
    const float* bl = (const float*)d_in[9];
    float* out = (float*)d_out;

    char* ws = (char*)d_ws;
    size_t off = 0;
    auto alloc = [&](size_t bytes) {
        void* p = ws + off;
        off = (off + bytes + 255) & ~(size_t)255;
        return p;
    };
    int* flag = (int*)alloc(256);
    int* src = (int*)alloc((size_t)NE * 4);
    int* dst = (int*)alloc((size_t)NE * 4);
    int* deg = (int*)alloc((size_t)NN * 4);
    float* dinv = (float*)alloc((size_t)NN * 4);
    int* row_ptr = (int*)alloc((size_t)(NN + 1) * 4);
    int* fill = (int*)alloc((size_t)NN * 4);
    int* block_sums = (int*)alloc((size_t)SCAN_BLOCKS * 4 + 256);
    int* csr_src = (int*)alloc((size_t)NE * 4);
    float* csr_w = (float*)alloc((size_t)NE * 4);
    ushort* h = (ushort*)alloc((size_t)NN * NH * 2);       // bf16 pre-aggregation features
    ushort* act_bf = (ushort*)alloc((size_t)NN * NH * 2);  // bf16 activations (layers 1,2)
    float* act_f = (float*)alloc((size_t)NN * NH * 4);     // f32 activations (layer 3)
    ushort* Wt1 = (ushort*)alloc((size_t)NF * NH * 2);
    ushort* Wt2 = (ushort*)alloc((size_t)NH * NH * 2);
    ushort* Wt3 = (ushort*)alloc((size_t)NH * NH * 2);
    (void)ws_size;

    // --- edge normalization + CSR build (once, reused for 3 layers) ---
    detect_dtype_kernel<<<1, 256, 0, stream>>>(ei, flag);
    convert_edges_kernel<<<(NE + 255) / 256, 256, 0, stream>>>(ei, src, dst, flag);
    hipMemsetAsync(deg, 0, (size_t)NN * 4, stream);
    hipMemsetAsync(fill, 0, (size_t)NN * 4, stream);
    deg_kernel<<<(NE + 255) / 256, 256, 0, stream>>>(dst, deg);
    dinv_kernel<<<(NN + 255) / 256, 256, 0, stream>>>(deg, dinv);
    scan1_kernel<<<SCAN_BLOCKS, 256, 0, stream>>>(deg, row_ptr, block_sums);
    scan2_kernel<<<1, 64, 0, stream>>>(block_sums);
    scan3_kernel<<<SCAN_BLOCKS, 256, 0, stream>>>(row_ptr, block_sums);
    fill_csr_kernel<<<(NE + 255) / 256, 256, 0, stream>>>(src, dst, dinv, row_ptr, fill,
                                                          csr_src, csr_w);

    // --- weight transpose+convert ---
    wtrans_kernel<<<NF / 8, 128, 0, stream>>>(W1, Wt1, NF);
    wtrans_kernel<<<NH / 8, 128, 0, stream>>>(W2, Wt2, NH);
    wtrans_kernel<<<NH / 8, 128, 0, stream>>>(W3, Wt3, NH);

    const int gemm_grid = (NN + BM - 1) / BM;
    const int agg_grid = (NN * 64 + 255) / 256;

    // layer 1: h = bf16(x @ W1); act_bf = relu(agg + selfloop + b1) in bf16
    gemm_mfma_kernel<1><<<gemm_grid, 256, 0, stream>>>(x, Wt1, h, NN, NF);
    aggregate_kernel<0, 1><<<agg_grid, 256, 0, stream>>>(h, row_ptr, csr_src, csr_w, dinv, b1,
                                                         act_bf);
    // layer 2
    gemm_mfma_kernel<0><<<gemm_grid, 256, 0, stream>>>(act_bf, Wt2, h, NN, NH);
    aggregate_kernel<0, 1><<<agg_grid, 256, 0, stream>>>(h, row_ptr, csr_src, csr_w, dinv, b2,
                                                         act_bf);
    // layer 3 (no relu, f32 out for classifier)
    gemm_mfma_kernel<0><<<gemm_grid, 256, 0, stream>>>(act_bf, Wt3, h, NN, NH);
    aggregate_kernel<1, 0><<<agg_grid, 256, 0, stream>>>(h, row_ptr, csr_src, csr_w, dinv, b3,
                                                         act_f);

    // classifier + log_softmax
    final_kernel<<<(NN + 255) / 256, 256, 0, stream>>>(act_f, Wl, bl, out);
}